// Round 2
// baseline (55.324 us; speedup 1.0000x reference)
//
#include <hip/hip_runtime.h>
#include <hip/hip_cooperative_groups.h>

namespace cg = cooperative_groups;

#define BN_EPS 1e-3f

// Fused single-launch kernel (cooperative):
//   Phase 1: per-node partial sums into d_ws
//     Si[b*N+n] = sum_f relu(feat[b,n,f]*inv[1+f]   + bias[1+f])   * w[1+f]
//     Sj[b*N+n] = sum_f relu(feat[b,n,f]*inv[1+F+f] + bias[1+F+f]) * w[1+F+f]
//     one wave per row (grid sized so nwaves == BN when possible)
//   grid.sync()
//   Phase 2: out[b,i,j] = relu(adj*inv0+bias0)*w0 + Si[b*N+i] + Sj[b*N+j] + cb
//     grid-stride float4 over flat [B*N*N] (N % 4 == 0)
__global__ __launch_bounds__(256) void fused_kernel(
    const float* __restrict__ feat,   // [B,N,F]
    const float* __restrict__ adj,    // [B,N,N]
    const float* __restrict__ gamma,
    const float* __restrict__ beta,
    const float* __restrict__ mean,
    const float* __restrict__ var,
    const float* __restrict__ w,
    const float* __restrict__ conv_b,
    float* __restrict__ out,
    float* __restrict__ Si,
    float* __restrict__ Sj,
    int F, int BN, int N, int total4)
{
    const int lane   = threadIdx.x & 63;
    const int wave   = (blockIdx.x * blockDim.x + threadIdx.x) >> 6;
    const int nwaves = (gridDim.x * blockDim.x) >> 6;

    // ---- Phase 1: node sums (one wave per row) ----
    // per-lane channel constants (lane == feature index; F <= 64 assumed)
    const bool active = (lane < F);
    const int  fl = active ? lane : (F - 1);
    const int  ci = 1 + fl;
    const int  cj = 1 + F + fl;
    const float invi = gamma[ci] * rsqrtf(var[ci] + BN_EPS);
    const float bi   = beta[ci] - mean[ci] * invi;
    const float wi   = w[ci];
    const float invj = gamma[cj] * rsqrtf(var[cj] + BN_EPS);
    const float bj   = beta[cj] - mean[cj] * invj;
    const float wj   = w[cj];

    for (int row = wave; row < BN; row += nwaves) {
        const float x = feat[(long long)row * F + fl];
        float vi = active ? fmaxf(fmaf(x, invi, bi), 0.0f) * wi : 0.0f;
        float vj = active ? fmaxf(fmaf(x, invj, bj), 0.0f) * wj : 0.0f;
        #pragma unroll
        for (int off = 32; off > 0; off >>= 1) {
            vi += __shfl_down(vi, off, 64);
            vj += __shfl_down(vj, off, 64);
        }
        if (lane == 0) {
            Si[row] = vi;
            Sj[row] = vj;
        }
    }

    cg::this_grid().sync();

    // ---- Phase 2: elementwise over adjacency ----
    const float inv0 = gamma[0] * rsqrtf(var[0] + BN_EPS);
    const float b0   = beta[0] - mean[0] * inv0;
    const float w0   = w[0];
    const float cb   = conv_b[0];

    const int nthr = gridDim.x * blockDim.x;
    for (int t = blockIdx.x * blockDim.x + threadIdx.x; t < total4; t += nthr) {
        const float4 a = reinterpret_cast<const float4*>(adj)[t];

        const int idx = t * 4;            // flat index into [B*N*N]
        const int row = idx / N;          // b*N + i
        const int b   = row / N;          // batch
        const int j0  = idx - row * N;

        const float si = Si[row] + cb;
        const float* sjp = Sj + b * N + j0;

        float4 r;
        r.x = fmaxf(fmaf(a.x, inv0, b0), 0.0f) * w0 + si + sjp[0];
        r.y = fmaxf(fmaf(a.y, inv0, b0), 0.0f) * w0 + si + sjp[1];
        r.z = fmaxf(fmaf(a.z, inv0, b0), 0.0f) * w0 + si + sjp[2];
        r.w = fmaxf(fmaf(a.w, inv0, b0), 0.0f) * w0 + si + sjp[3];

        reinterpret_cast<float4*>(out)[t] = r;
    }
}

extern "C" void kernel_launch(void* const* d_in, const int* in_sizes, int n_in,
                              void* d_out, int out_size, void* d_ws, size_t ws_size,
                              hipStream_t stream) {
    const float* feat  = (const float*)d_in[0];   // [B,N,F]
    const float* adj   = (const float*)d_in[1];   // [B,N,N]
    const float* gamma = (const float*)d_in[2];   // [C]
    const float* beta  = (const float*)d_in[3];
    const float* mean  = (const float*)d_in[4];
    const float* var   = (const float*)d_in[5];
    const float* w     = (const float*)d_in[6];
    const float* cb    = (const float*)d_in[7];   // [1]
    float* out = (float*)d_out;

    const int C  = in_sizes[2];
    int F  = (C - 1) / 2;                         // 64
    int BN = in_sizes[0] / F;                     // B*N = 2048
    const long long total = in_sizes[1];          // B*N*N
    int N  = (int)(total / BN);                   // 512
    int total4 = (int)(total / 4);

    float* Si = (float*)d_ws;                     // BN floats
    float* Sj = Si + BN;                          // BN floats

    // 512 blocks x 256 threads = 2048 waves (== BN rows), 2 blocks/CU —
    // safely co-resident for cooperative launch at this register footprint.
    int blocks = 512;

    void* args[] = {
        (void*)&feat, (void*)&adj, (void*)&gamma, (void*)&beta,
        (void*)&mean, (void*)&var, (void*)&w, (void*)&cb,
        (void*)&out, (void*)&Si, (void*)&Sj,
        (void*)&F, (void*)&BN, (void*)&N, (void*)&total4
    };
    hipLaunchCooperativeKernel((void*)fused_kernel, dim3(blocks), dim3(256),
                               args, 0, stream);
}

// Round 3
// 12.677 us; speedup vs baseline: 4.3643x; 4.3643x over previous
//
#include <hip/hip_runtime.h>

#define BN_EPS 1e-3f
#define RPB   8      // output rows per block (256 threads / 32 lanes-per-row)
#define MAXN  512
#define MAXF  64

// Single-launch fused kernel, no grid sync.
// Block = (batch b, 8 consecutive output rows i0..i0+7).
//   stage 1: per-channel BN constants -> LDS
//   stage 2: Sj_l[0..N-1] for batch b (thread-per-row, float4 feat loads, L2-hit)
//            Si_l[0..7]   for own rows (wave-per-row shuffle reduce)
//   stage 3: out[b,i,j] = relu(adj*inv0+b0)*w0 + Si_l[i-i0] + Sj_l[j] + cb
//            float4, 32 lanes per row, coalesced.
__global__ __launch_bounds__(256) void fused_kernel(
    const float* __restrict__ feat,   // [B,N,F]
    const float* __restrict__ adj,    // [B,N,N]
    const float* __restrict__ gamma,
    const float* __restrict__ beta,
    const float* __restrict__ mean,
    const float* __restrict__ var,
    const float* __restrict__ w,
    const float* __restrict__ conv_b,
    float* __restrict__ out,
    int N, int F)
{
    __shared__ float sInvI[MAXF], sBi[MAXF], sWi[MAXF];
    __shared__ float sInvJ[MAXF], sBj[MAXF], sWj[MAXF];
    __shared__ float Sj_l[MAXN];
    __shared__ float Si_l[RPB];

    const int tid = threadIdx.x;
    const int bpb = N / RPB;                      // blocks per batch
    const int b   = blockIdx.x / bpb;
    const int i0  = (blockIdx.x - b * bpb) * RPB;

    // ---- stage 1: BN/conv per-channel constants ----
    if (tid < F) {
        const int ci = 1 + tid, cj = 1 + F + tid;
        const float gi = gamma[ci] * rsqrtf(var[ci] + BN_EPS);
        sInvI[tid] = gi;
        sBi[tid]   = beta[ci] - mean[ci] * gi;
        sWi[tid]   = w[ci];
        const float gj = gamma[cj] * rsqrtf(var[cj] + BN_EPS);
        sInvJ[tid] = gj;
        sBj[tid]   = beta[cj] - mean[cj] * gj;
        sWj[tid]   = w[cj];
    }
    __syncthreads();

    const float* fb = feat + (long long)b * N * F;

    // ---- stage 2a: Sj for ALL rows of this batch (thread-per-row) ----
    for (int r = tid; r < N; r += blockDim.x) {
        const float4* fr = reinterpret_cast<const float4*>(fb + (long long)r * F);
        float acc = 0.f;
        #pragma unroll
        for (int f4 = 0; f4 < (MAXF >> 2); ++f4) {
            if (f4 >= (F >> 2)) break;
            const float4 x  = fr[f4];
            const float4 iv = reinterpret_cast<const float4*>(sInvJ)[f4];
            const float4 bb = reinterpret_cast<const float4*>(sBj)[f4];
            const float4 ww = reinterpret_cast<const float4*>(sWj)[f4];
            acc += fmaxf(fmaf(x.x, iv.x, bb.x), 0.f) * ww.x;
            acc += fmaxf(fmaf(x.y, iv.y, bb.y), 0.f) * ww.y;
            acc += fmaxf(fmaf(x.z, iv.z, bb.z), 0.f) * ww.z;
            acc += fmaxf(fmaf(x.w, iv.w, bb.w), 0.f) * ww.w;
        }
        Sj_l[r] = acc;
    }

    // ---- stage 2b: Si for own RPB rows (wave-per-row, lane = feature) ----
    {
        const int wv = tid >> 6, ln = tid & 63;
        for (int k = wv; k < RPB; k += (256 >> 6)) {
            const int r = i0 + k;
            float v = 0.f;
            if (ln < F) {
                const float x = fb[(long long)r * F + ln];
                v = fmaxf(fmaf(x, sInvI[ln], sBi[ln]), 0.f) * sWi[ln];
            }
            #pragma unroll
            for (int off = 32; off > 0; off >>= 1)
                v += __shfl_down(v, off, 64);
            if (ln == 0) Si_l[k] = v;
        }
    }
    __syncthreads();

    // ---- stage 3: elementwise output over own 8 adjacency rows ----
    const float inv0 = gamma[0] * rsqrtf(var[0] + BN_EPS);
    const float b0   = beta[0] - mean[0] * inv0;
    const float w0   = w[0];
    const float cb   = conv_b[0];

    const int il  = tid >> 5;                  // 0..7: local row
    const int l32 = tid & 31;
    const long long rowbase = ((long long)b * N + i0 + il) * N;
    const float4* arow = reinterpret_cast<const float4*>(adj + rowbase);
    float4*       orow = reinterpret_cast<float4*>(out + rowbase);
    const float4* sj4  = reinterpret_cast<const float4*>(Sj_l);
    const float   si   = Si_l[il] + cb;

    const int n4 = N >> 2;
    for (int j4 = l32; j4 < n4; j4 += 32) {
        const float4 a = arow[j4];
        const float4 s = sj4[j4];
        float4 r;
        r.x = fmaxf(fmaf(a.x, inv0, b0), 0.f) * w0 + si + s.x;
        r.y = fmaxf(fmaf(a.y, inv0, b0), 0.f) * w0 + si + s.y;
        r.z = fmaxf(fmaf(a.z, inv0, b0), 0.f) * w0 + si + s.z;
        r.w = fmaxf(fmaf(a.w, inv0, b0), 0.f) * w0 + si + s.w;
        orow[j4] = r;
    }
}

extern "C" void kernel_launch(void* const* d_in, const int* in_sizes, int n_in,
                              void* d_out, int out_size, void* d_ws, size_t ws_size,
                              hipStream_t stream) {
    const float* feat  = (const float*)d_in[0];   // [B,N,F]
    const float* adj   = (const float*)d_in[1];   // [B,N,N]
    const float* gamma = (const float*)d_in[2];   // [C]
    const float* beta  = (const float*)d_in[3];
    const float* mean  = (const float*)d_in[4];
    const float* var   = (const float*)d_in[5];
    const float* w     = (const float*)d_in[6];
    const float* cb    = (const float*)d_in[7];   // [1]

    const int C  = in_sizes[2];
    const int F  = (C - 1) / 2;                   // 64
    const int BN = in_sizes[0] / F;               // B*N = 2048
    const long long total = in_sizes[1];          // B*N*N
    const int N  = (int)(total / BN);             // 512
    const int B  = BN / N;                        // 4

    const int blocks = B * (N / RPB);             // 256

    fused_kernel<<<blocks, 256, 0, stream>>>(feat, adj, gamma, beta, mean, var,
                                             w, cb, (float*)d_out, N, F);
}